// Round 22
// baseline (37.597 us; speedup 1.0000x reference)
//
#include <hip/hip_runtime.h>

// input x: (B=256,T=600,J=25,C=3) f32; x[b,tt,n*5+p,c] = in[(b*600+tt)*75 + n*15 + p*3 + c]
// output: (B,5,1800,4,4) f32, 3 window groups g: tout = g*600+tt.
//
// R22 = R21 (35.6us) + DMA-pipelined 2-chunk blocks. Block = (b, chunk pair 2j,2j+1).
// DMA c0 -> sync -> ISSUE DMA c1 -> compute/store c0 -> s_waitcnt vmcnt(8)
// (in-order vmcnt retire: <=8 outstanding => the 4 oldest ops = c1's DMAs done;
// waves issue 11-12 stores after the DMAs so vmcnt(8) is always safe) -> barrier
// -> compute/store c1. c1's stage latency hides under c0's compute+store.
// obuf is OVERLAID on the current raw buffer (stride-4 + rotation, R19-proven):
// LDS = 2 x 32.8KB = 65.6KB -> 2 blocks/CU.

#define T_ 600
#define CH_ 100

typedef float fx4 __attribute__((ext_vector_type(4)));
typedef const __attribute__((address_space(1))) void* gas_t;
typedef __attribute__((address_space(3))) void* las_t;

// LDS-only barrier: order LDS ops but let global (stores + DMA) stay in flight.
#define BAR_LDS() do { asm volatile("s_waitcnt lgkmcnt(0)" ::: "memory"); \
                       __builtin_amdgcn_s_barrier(); } while (0)

// issue 4 wave-uniform-dest DMA instrs staging chunk tc's row superset
__device__ __forceinline__ void stage_issue(const float* __restrict__ x,
                                            float4* raw4, int b, int tc,
                                            int tid, int wv) {
    int s_row = (tc > 0) ? tc - 1 : 0;
    int e_row = tc + CH_ + 1; if (e_row > T_) e_row = T_;
    int r0  = (b * 600 + s_row) * 75;
    int a0  = r0 & ~3;
    int nfl = (r0 - a0) + (e_row - s_row) * 75;
    int n4  = (nfl + 3) >> 2;                       // <= 1914
    const float4* srcv = reinterpret_cast<const float4*>(x);
    int base4 = a0 >> 2;
    #pragma unroll
    for (int i = 0; i < 4; ++i) {
        int e  = i * 512 + tid;
        int g4 = base4 + ((e < n4) ? e : (n4 - 1)); // clamp source; dest -> slack
        float4* ldst = raw4 + (i * 512 + wv * 64);  // wave-uniform LDS base
        __builtin_amdgcn_global_load_lds((gas_t)(srcv + g4), (las_t)ldst, 16, 0, 0);
    }
}

__device__ __forceinline__ void process_chunk(float4* lds4, fx4* outf4,
                                              int b, int ch, int tid) {
    float* raw = reinterpret_cast<float*>(lds4);
    int tc = ch * CH_;
    int vtt1 = -1, vtt2 = -1;
    switch (ch) {
        case 0: vtt1 = 0;   break;
        case 1: vtt1 = 199; break;
        case 2: vtt1 = 200; vtt2 = 299; break;
        case 3: vtt1 = 300; vtt2 = 399; break;
        case 4: vtt1 = 400; break;
        case 5: vtt1 = 599; break;
    }
    int s_row = (tc > 0) ? tc - 1 : 0;
    int off   = ((b * 600 + s_row) * 75) & 3;

    const float w5[5] = {4.f, 2.f, 3.f, 2.f, 4.f};

    // ---- compute: ONE batch of 510 unique slots -> 9 registers ----
    bool active = (tid < 510);
    float e00=0.f,e01=0.f,e02=0.f,e11=0.f,e12=0.f,e22=0.f,mu0=0.f,mu1=0.f,mu2=0.f;
    if (active) {
        bool isvar = (tid >= 500);
        int n, tt;
        if (!isvar) { n = tid / 100; tt = tc + (tid - n * 100); }
        else if (tid < 505) { n = tid - 500; tt = (vtt1 < 0) ? tc : vtt1; }
        else                { n = tid - 505; tt = (vtt2 < 0) ? tc : vtt2; }

        int midoff = off + (tt - s_row) * 75 + n * 15;
        const float* rc  = &raw[midoff];
        const float* r0p = rc - 75;    // valid for all interior slots
        const float* r1p = rc + 75;

        float s0=0.f,s1=0.f,s2=0.f, m0=0.f,m1=0.f,m2=0.f;
        float A00=0.f,A01=0.f,A02=0.f,A11=0.f,A12=0.f,A22=0.f;
        #pragma unroll
        for (int p = 0; p < 5; ++p) {
            float a = rc[p*3+0], c = rc[p*3+1], d = rc[p*3+2];
            s0 += a; s1 += c; s2 += d;
            m0 += w5[p]*a; m1 += w5[p]*c; m2 += w5[p]*d;
            A00 += a*a; A01 += a*c; A02 += a*d;
            A11 += c*c; A12 += c*d; A22 += d*d;
        }
        mu0 = m0*(1.f/15.f); mu1 = m1*(1.f/15.f); mu2 = m2*(1.f/15.f);

        float inv = 0.2f;
        if (!isvar) {
            #pragma unroll
            for (int dstep = 0; dstep < 2; ++dstep) {
                const float* rn = dstep ? r1p : r0p;
                #pragma unroll
                for (int p = 0; p < 5; ++p) {
                    float a = rn[p*3+0], c = rn[p*3+1], d = rn[p*3+2];
                    s0 += a; s1 += c; s2 += d;
                    A00 += a*a; A01 += a*c; A02 += a*d;
                    A11 += c*c; A12 += c*d; A22 += d*d;
                }
            }
            inv = 1.f/15.f;
        }

        float mb0 = s0*inv, mb1 = s1*inv, mb2 = s2*inv;
        e00 = A00*inv - 2.f*mu0*mb0 + 2.f*mu0*mu0;
        e01 = A01*inv - mu0*mb1 - mb0*mu1 + 2.f*mu0*mu1;
        e02 = A02*inv - mu0*mb2 - mb0*mu2 + 2.f*mu0*mu2;
        e11 = A11*inv - 2.f*mu1*mb1 + 2.f*mu1*mu1;
        e12 = A12*inv - mu1*mb2 - mb1*mu2 + 2.f*mu1*mu2;
        e22 = A22*inv - 2.f*mu2*mb2 + 2.f*mu2*mu2;
    }
    BAR_LDS();   // all raw reads complete before overlay overwrite

    // ---- overlay deduped blocks over this raw buffer (stride-4, rotated) ----
    if (active) {
        int o4 = tid * 4;
        lds4[o4 + ((0 + tid) & 3)] = make_float4(e00, e01, e02, mu0);
        lds4[o4 + ((1 + tid) & 3)] = make_float4(e01, e11, e12, mu1);
        lds4[o4 + ((2 + tid) & 3)] = make_float4(e02, e12, e22, mu2);
        lds4[o4 + ((3 + tid) & 3)] = make_float4(mu0, mu1, mu2, 1.f);
    }
    BAR_LDS();

    // ---- store: 1500 slots x 4 pieces, lane-contiguous nontemporal ----
    #pragma unroll
    for (int k = 0; k < 12; ++k) {
        int f = k * 512 + tid;
        if (f < 6000) {
            int sl = f >> 2, pc = f & 3;
            int n  = sl / 300;
            int q  = sl - n * 300;
            int w  = q / 100;
            int tl = q - w * 100;
            int tt = tc + tl;
            bool bd;
            if (w == 0)      bd = (tt == 0) || (tt == 599);
            else if (w == 1) { int r = tt % 300; bd = (r == 0) || (r == 299); }
            else             { int r = tt % 200; bd = (r == 0) || (r == 199); }
            int oi;
            if (!bd)             oi = n * 100 + tl;
            else if (tt == vtt1) oi = 500 + n;
            else                 oi = 505 + n;
            size_t o = ((size_t)(b * 5 + n) * 1800 + w * 600 + tt) * 4 + pc;
            float4 v = lds4[oi * 4 + ((pc + oi) & 3)];
            fx4 nv; nv.x = v.x; nv.y = v.y; nv.z = v.z; nv.w = v.w;
            __builtin_nontemporal_store(nv, &outf4[o]);
        }
    }
}

__global__ __launch_bounds__(512) void gauss_agg_kernel(const float* __restrict__ x,
                                                        float* __restrict__ out) {
    __shared__ float4 rawA[2048];   // 32.8 KB (chunk superset + clamp slack)
    __shared__ float4 rawB[2048];   // 32.8 KB

    int blk = blockIdx.x;           // 768 = 256 b * 3 pairs
    int j   = blk % 3;
    int b   = blk / 3;
    int c0  = 2 * j, c1 = 2 * j + 1;
    int tid = (int)threadIdx.x;
    int wv  = tid >> 6;
    fx4* outf4 = reinterpret_cast<fx4*>(out);

    stage_issue(x, rawA, b, c0 * CH_, tid, wv);
    __syncthreads();                          // drain c0 DMA (block start: free)

    stage_issue(x, rawB, b, c1 * CH_, tid, wv);   // issue only; hides under c0 work

    process_chunk(rawA, outf4, b, c0, tid);

    // wait c1's 4 DMAs (oldest ops): <=8 outstanding of the 15-16 issued
    asm volatile("s_waitcnt vmcnt(8)" ::: "memory");
    __builtin_amdgcn_s_barrier();

    process_chunk(rawB, outf4, b, c1, tid);
}

extern "C" void kernel_launch(void* const* d_in, const int* in_sizes, int n_in,
                              void* d_out, int out_size, void* d_ws, size_t ws_size,
                              hipStream_t stream) {
    const float* x = (const float*)d_in[0];
    float* out = (float*)d_out;
    gauss_agg_kernel<<<768, 512, 0, stream>>>(x, out);
}

// Round 23
// 36.619 us; speedup vs baseline: 1.0267x; 1.0267x over previous
//
#include <hip/hip_runtime.h>

// input x: (B=256,T=600,J=25,C=3) f32; x[b,tt,n*5+p,c] = in[(b*600+tt)*75 + n*15 + p*3 + c]
// output: (B,5,1800,4,4) f32, 3 window groups g: tout = g*600+tt.
//
// R23 = R21 (35.6us) + clean DMA pipelining. Block = (b, half): 3 chunks of 100.
// Per chunk: compute -> lgkm-barrier -> ISSUE next chunk's DMA into raw (raw
// reads done; obuf separate) -> 12-store sweep (hides DMA latency) ->
// s_waitcnt vmcnt(12) + barrier (per-wave 4 DMA + 12 stores outstanding:
// waiting to 12 retires exactly the DMAs, no store drain) -> next compute.
// Only chunk 0's stage is exposed (1/3 vs 3/3 in R21).

#define T_ 600
#define CH_ 100

typedef float fx4 __attribute__((ext_vector_type(4)));
typedef const __attribute__((address_space(1))) void* gas_t;
typedef __attribute__((address_space(3))) void* las_t;

// LDS-only barrier: order LDS ops but let global (stores + DMA) stay in flight.
#define BAR_LDS() do { asm volatile("s_waitcnt lgkmcnt(0)" ::: "memory"); \
                       __builtin_amdgcn_s_barrier(); } while (0)

// issue 4 wave-uniform-dest DMA instrs staging chunk tc's row superset into raw4
__device__ __forceinline__ void stage_issue(const float* __restrict__ x,
                                            float4* raw4, int b, int tc,
                                            int tid, int wv) {
    int s_row = (tc > 0) ? tc - 1 : 0;
    int e_row = tc + CH_ + 1; if (e_row > T_) e_row = T_;
    int r0  = (b * 600 + s_row) * 75;
    int a0  = r0 & ~3;
    int nfl = (r0 - a0) + (e_row - s_row) * 75;
    int n4  = (nfl + 3) >> 2;                       // <= 1914
    const float4* srcv = reinterpret_cast<const float4*>(x);
    int base4 = a0 >> 2;
    #pragma unroll
    for (int i = 0; i < 4; ++i) {
        int e  = i * 512 + tid;
        int g4 = base4 + ((e < n4) ? e : (n4 - 1)); // clamp source; dest -> slack
        float4* ldst = raw4 + (i * 512 + wv * 64);  // wave-uniform LDS base
        __builtin_amdgcn_global_load_lds((gas_t)(srcv + g4), (las_t)ldst, 16, 0, 0);
    }
}

__global__ __launch_bounds__(512) void gauss_agg_kernel(const float* __restrict__ x,
                                                        float* __restrict__ out) {
    __shared__ float4 raw4[2048];      // 32.8 KB staged superset (+clamp slack)
    __shared__ float4 obuf[512 * 5];   // 40 KB; 80B/slot stride avoids bank degeneracy
    float* raw = reinterpret_cast<float*>(raw4);

    int blk  = blockIdx.x;             // 512 = 256 b * 2 halves
    int half = blk & 1;
    int b    = blk >> 1;
    int tid  = (int)threadIdx.x;
    int wv   = tid >> 6;
    fx4* outf4 = reinterpret_cast<fx4*>(out);
    const float w5[5] = {4.f, 2.f, 3.f, 2.f, 4.f};

    // prologue: stage first chunk (only exposed stage of this block)
    stage_issue(x, raw4, b, half * 300, tid, wv);
    __syncthreads();   // drains the 4 DMAs; no other vm ops outstanding yet

    for (int i = 0; i < 3; ++i) {
        int ch = half * 3 + i;
        int tc = ch * CH_;
        int vtt1 = -1, vtt2 = -1;
        switch (ch) {
            case 0: vtt1 = 0;   break;
            case 1: vtt1 = 199; break;
            case 2: vtt1 = 200; vtt2 = 299; break;
            case 3: vtt1 = 300; vtt2 = 399; break;
            case 4: vtt1 = 400; break;
            case 5: vtt1 = 599; break;
        }
        int s_row = (tc > 0) ? tc - 1 : 0;
        int off   = ((b * 600 + s_row) * 75) & 3;

        // ---- compute: ONE batch of 510 unique slots ----
        if (tid < 510) {
            bool isvar = (tid >= 500);
            int n, tt;
            if (!isvar) { n = tid / 100; tt = tc + (tid - n * 100); }
            else if (tid < 505) { n = tid - 500; tt = (vtt1 < 0) ? tc : vtt1; }
            else                { n = tid - 505; tt = (vtt2 < 0) ? tc : vtt2; }

            int midoff = off + (tt - s_row) * 75 + n * 15;
            const float* rc  = &raw[midoff];
            const float* r0p = rc - 75;    // valid for all interior slots
            const float* r1p = rc + 75;

            float s0=0.f,s1=0.f,s2=0.f, m0=0.f,m1=0.f,m2=0.f;
            float A00=0.f,A01=0.f,A02=0.f,A11=0.f,A12=0.f,A22=0.f;
            #pragma unroll
            for (int p = 0; p < 5; ++p) {
                float a = rc[p*3+0], c = rc[p*3+1], d = rc[p*3+2];
                s0 += a; s1 += c; s2 += d;
                m0 += w5[p]*a; m1 += w5[p]*c; m2 += w5[p]*d;
                A00 += a*a; A01 += a*c; A02 += a*d;
                A11 += c*c; A12 += c*d; A22 += d*d;
            }
            float mu0 = m0*(1.f/15.f), mu1 = m1*(1.f/15.f), mu2 = m2*(1.f/15.f);

            float inv = 0.2f;
            if (!isvar) {
                #pragma unroll
                for (int dstep = 0; dstep < 2; ++dstep) {
                    const float* rn = dstep ? r1p : r0p;
                    #pragma unroll
                    for (int p = 0; p < 5; ++p) {
                        float a = rn[p*3+0], c = rn[p*3+1], d = rn[p*3+2];
                        s0 += a; s1 += c; s2 += d;
                        A00 += a*a; A01 += a*c; A02 += a*d;
                        A11 += c*c; A12 += c*d; A22 += d*d;
                    }
                }
                inv = 1.f/15.f;
            }

            float mb0 = s0*inv, mb1 = s1*inv, mb2 = s2*inv;
            float e00 = A00*inv - 2.f*mu0*mb0 + 2.f*mu0*mu0;
            float e01 = A01*inv - mu0*mb1 - mb0*mu1 + 2.f*mu0*mu1;
            float e02 = A02*inv - mu0*mb2 - mb0*mu2 + 2.f*mu0*mu2;
            float e11 = A11*inv - 2.f*mu1*mb1 + 2.f*mu1*mu1;
            float e12 = A12*inv - mu1*mb2 - mb1*mu2 + 2.f*mu1*mu2;
            float e22 = A22*inv - 2.f*mu2*mb2 + 2.f*mu2*mu2;

            int base = tid * 5;
            obuf[base + 0] = make_float4(e00, e01, e02, mu0);
            obuf[base + 1] = make_float4(e01, e11, e12, mu1);
            obuf[base + 2] = make_float4(e02, e12, e22, mu2);
            obuf[base + 3] = make_float4(mu0, mu1, mu2, 1.f);
        }
        BAR_LDS();   // raw reads + obuf writes complete

        // ---- issue next chunk's DMA into raw (hides under the store sweep) ----
        if (i < 2) stage_issue(x, raw4, b, tc + CH_, tid, wv);

        // ---- store: 1500 slots x 4 pieces, lane-contiguous nontemporal ----
        #pragma unroll
        for (int k = 0; k < 12; ++k) {
            int f = k * 512 + tid;
            if (f < 6000) {
                int sl = f >> 2, pc = f & 3;
                int n  = sl / 300;
                int q  = sl - n * 300;
                int w  = q / 100;
                int tl = q - w * 100;
                int tt = tc + tl;
                bool bd;
                if (w == 0)      bd = (tt == 0) || (tt == 599);
                else if (w == 1) { int r = tt % 300; bd = (r == 0) || (r == 299); }
                else             { int r = tt % 200; bd = (r == 0) || (r == 199); }
                int oi;
                if (!bd)             oi = n * 100 + tl;
                else if (tt == vtt1) oi = 500 + n;
                else                 oi = 505 + n;
                size_t o = ((size_t)(b * 5 + n) * 1800 + w * 600 + tt) * 4 + pc;
                float4 v = obuf[oi * 5 + pc];
                fx4 nv; nv.x = v.x; nv.y = v.y; nv.z = v.z; nv.w = v.w;
                __builtin_nontemporal_store(nv, &outf4[o]);
            }
        }

        // ---- wait for the 4 DMAs only (12 current stores may stay in flight) ----
        if (i < 2) {
            asm volatile("s_waitcnt vmcnt(12)" ::: "memory");
            __builtin_amdgcn_s_barrier();
        }
    }
}

extern "C" void kernel_launch(void* const* d_in, const int* in_sizes, int n_in,
                              void* d_out, int out_size, void* d_ws, size_t ws_size,
                              hipStream_t stream) {
    const float* x = (const float*)d_in[0];
    float* out = (float*)d_out;
    gauss_agg_kernel<<<512, 512, 0, stream>>>(x, out);
}